// Round 4
// baseline (401.686 us; speedup 1.0000x reference)
//
#include <hip/hip_runtime.h>
#include <hip/hip_bf16.h>

// VectorQuantizer on MI355X (gfx950), round 4.
// argmin_k ||e_k||^2 - 2 x.e_k via bf16 MFMA 16x16x32.
// R4: ZERO-barrier structure. Each wave owns one (b,h) line (64 rows x all
// 1024 codes): A-frags resident in 128 VGPRs, B-frags streamed L2->registers
// (no LDS, no global_load_lds, no __syncthreads in the K-loop). Phase 2 uses
// per-wave-private LDS slices (wave-internal lgkmcnt ordering only).
// Grid = 512 blocks = 2/CU exactly, single generation.

#define DIN 256
#define NCODES 1024

typedef __attribute__((ext_vector_type(8))) short short8;
typedef __attribute__((ext_vector_type(4))) float float4v;
typedef __attribute__((ext_vector_type(2))) float float2v;
typedef __attribute__((ext_vector_type(4))) unsigned short ushort4v;

static __device__ __forceinline__ unsigned short f2bf(float f) {
  unsigned int u = __float_as_uint(f);
  unsigned int r = (u + 0x7fffu + ((u >> 16) & 1u)) >> 16;  // RNE
  return (unsigned short)r;
}

// ---- prep: codebook fp32 -> bf16 k-major [chunk8][code][8] + norms ----
__global__ void vq_prep(const float* __restrict__ e,
                        unsigned short* __restrict__ e_bf2,
                        float* __restrict__ norms) {
  int wave = threadIdx.x >> 6, lane = threadIdx.x & 63;
  int k = blockIdx.x * 4 + wave;               // 256 blocks * 4 codes
  float4v v = ((const float4v*)(e + k * DIN))[lane];
  float ss = v[0]*v[0] + v[1]*v[1] + v[2]*v[2] + v[3]*v[3];
  ushort4v pk;
  pk[0] = f2bf(v[0]); pk[1] = f2bf(v[1]); pk[2] = f2bf(v[2]); pk[3] = f2bf(v[3]);
  int cc = lane >> 1, sub = lane & 1;          // d-chunk of 8, half
  *(ushort4v*)(e_bf2 + (cc * NCODES + k) * 8 + sub * 4) = pk;
  #pragma unroll
  for (int m = 1; m < 64; m <<= 1) ss += __shfl_xor(ss, m, 64);
  if (lane == 0) norms[k] = ss;
}

// ---- main: one wave per (b,h) line; 64 rows x 1024 codes, no barriers ----
__global__ void __launch_bounds__(256, 2)
vq_main(const float* __restrict__ xin, const float* __restrict__ e_fp,
        const unsigned short* __restrict__ e_bf2, const float* __restrict__ norms,
        float* __restrict__ out, float* __restrict__ loss_acc) {
  __shared__ float qs[4][64 * 66];             // per-wave transpose slices
  __shared__ int   fi[4][64];                  // per-wave chosen indices

  const int tid  = threadIdx.x;
  const int wave = tid >> 6, lane = tid & 63;
  const int m16  = lane & 15, quad = lane >> 4;
  const int line = blockIdx.x * 4 + wave;      // 512 blocks * 4 = 2048 lines
  const int b    = line >> 6, h = line & 63;
  const int base = b * 1048576 + h * 64;       // + d*4096 + w

  // ---- A fragments: 64 rows x 256 d, global -> 32x short8 (128 VGPRs) ----
  short8 areg[32];
  #pragma unroll
  for (int i = 0; i < 4; ++i) {
    int r = i * 16 + m16;
    #pragma unroll
    for (int kk = 0; kk < 8; ++kk) {
      int d0 = (kk * 4 + quad) * 8;
      short8 pk;
      #pragma unroll
      for (int ii = 0; ii < 8; ++ii)
        pk[ii] = (short)f2bf(xin[base + (d0 + ii) * 4096 + r]);
      areg[i * 8 + kk] = pk;
    }
  }

  float bestv[4][4];
  int   besti[4][4];
  float4v acc[4];
  #pragma unroll
  for (int i = 0; i < 4; ++i) {
    #pragma unroll
    for (int r = 0; r < 4; ++r) { bestv[i][r] = INFINITY; besti[i][r] = 0; }
    acc[i] = (float4v)(0.0f);
  }

  // ---- K-loop: 64 code-steps of 16 codes, B streamed L2 -> registers ----
  for (int cs = 0; cs < 64; ++cs) {
    int c0 = cs * 16;
    short8 bfr[8];
    #pragma unroll
    for (int kk = 0; kk < 8; ++kk)
      bfr[kk] = *(const short8*)(e_bf2 + ((kk * 4 + quad) * NCODES + c0 + m16) * 8);
    float nj = norms[c0 + m16];
    #pragma unroll
    for (int kk = 0; kk < 8; ++kk) {
      #pragma unroll
      for (int i = 0; i < 4; ++i)
        acc[i] = __builtin_amdgcn_mfma_f32_16x16x32_bf16(areg[i * 8 + kk], bfr[kk], acc[i], 0, 0, 0);
    }
    int col = c0 + m16;
    #pragma unroll
    for (int i = 0; i < 4; ++i) {
      #pragma unroll
      for (int r = 0; r < 4; ++r) {
        float s = nj - 2.0f * acc[i][r];
        if (s < bestv[i][r]) { bestv[i][r] = s; besti[i][r] = col; }
      }
      acc[i] = (float4v)(0.0f);
    }
  }

  // ---- cross-lane argmin over the 16 col-lanes (tie -> smaller idx) ----
  #pragma unroll
  for (int msk = 1; msk <= 8; msk <<= 1) {
    #pragma unroll
    for (int i = 0; i < 4; ++i)
      #pragma unroll
      for (int r = 0; r < 4; ++r) {
        float ov = __shfl_xor(bestv[i][r], msk, 64);
        int   oi = __shfl_xor(besti[i][r], msk, 64);
        if (ov < bestv[i][r] || (ov == bestv[i][r] && oi < besti[i][r])) {
          bestv[i][r] = ov; besti[i][r] = oi;
        }
      }
  }
  if (m16 == 0) {
    #pragma unroll
    for (int i = 0; i < 4; ++i)
      #pragma unroll
      for (int r = 0; r < 4; ++r)
        fi[wave][i * 16 + quad * 4 + r] = besti[i][r];
  }
  __asm__ volatile("s_waitcnt lgkmcnt(0)" ::: "memory");  // wave-internal LDS order

  // ---- phase 2 (per-wave private slice): gather fp32 e, transpose, write+loss
  float* qsw = qs[wave];
  const int* fiw = fi[wave];
  float lsum = 0.0f;
  const int wq = lane & 31, dh = lane >> 5;
  for (int h2 = 0; h2 < 4; ++h2) {             // 4 chunks of 64 d
    #pragma unroll
    for (int jj = 0; jj < 16; ++jj) {          // gather 4 rows x 64 d per iter
      int w2 = jj * 4 + quad;
      int idx = fiw[w2];
      float4v qv = *(const float4v*)(e_fp + idx * DIN + h2 * 64 + m16 * 4);
      #pragma unroll
      for (int ii = 0; ii < 4; ++ii)
        qsw[(m16 * 4 + ii) * 66 + w2] = qv[ii];
    }
    __asm__ volatile("s_waitcnt lgkmcnt(0)" ::: "memory");
    #pragma unroll
    for (int dd = 0; dd < 32; ++dd) {          // coalesced writes + exact loss
      int dL = dd * 2 + dh;
      int g = base + (h2 * 64 + dL) * 4096 + wq * 2;
      float2v q  = *(float2v*)(qsw + dL * 66 + wq * 2);
      float2v xv = *(const float2v*)(xin + g);
      out[1 + g] = q[0];
      out[2 + g] = q[1];
      float d0 = q[0] - xv[0], d1 = q[1] - xv[1];
      lsum += d0 * d0 + d1 * d1;
    }
    __asm__ volatile("s_waitcnt lgkmcnt(0)" ::: "memory");
  }

  #pragma unroll
  for (int msk = 1; msk < 64; msk <<= 1) lsum += __shfl_xor(lsum, msk, 64);
  if (lane == 0) atomicAdd(loss_acc, lsum);
}

__global__ void vq_fin(const float* __restrict__ loss_acc,
                       const float* __restrict__ beta,
                       float* __restrict__ out) {
  out[0] = (1.0f + beta[0]) * loss_acc[0] / 33554432.0f;
}

extern "C" void kernel_launch(void* const* d_in, const int* in_sizes, int n_in,
                              void* d_out, int out_size, void* d_ws, size_t ws_size,
                              hipStream_t stream) {
  const float* xin  = (const float*)d_in[0];
  const float* emb  = (const float*)d_in[1];
  const float* beta = (const float*)d_in[2];
  float* out = (float*)d_out;
  float* loss_acc = (float*)d_ws;                                // 4 B
  float* norms = (float*)((char*)d_ws + 4096);                   // 4 KB
  unsigned short* e_bf2 = (unsigned short*)((char*)d_ws + 8192); // 512 KB k-major

  hipMemsetAsync(d_ws, 0, 4, stream);
  vq_prep<<<256, 256, 0, stream>>>(emb, e_bf2, norms);
  vq_main<<<512, 256, 0, stream>>>(xin, emb, e_bf2, norms, out, loss_acc);
  vq_fin<<<1, 1, 0, stream>>>(loss_acc, beta, out);
}